// Round 11
// baseline (234.425 us; speedup 1.0000x reference)
//
#include <hip/hip_runtime.h>
#include <cstdint>

// ---------------------------------------------------------------------------
// CrossAttentionBlock: q/k/v proj (bf16 MFMA; K/V rows zeroed where masked;
// Q pre-scaled by log2(e)/8) -> flash attention (32x32 MFMA, exp2-only
// softmax, double-buffered DMA staging, 2 qsub x 4 kvsub wave split,
// in-block merge, in-kernel normalize + transpose + direct AO write)
// -> o proj (split-K=2, fp32 partials) -> LayerNorm (sums partials + bias
// + residual).  B=2,SQ=1024,SKV=4096,E=1024,H=16,D=64.
// Softmax: p = 2^(s') with s' = K·(Q*log2(e)/8) bounded (|s'|<~10).
// Masked kv have K=V=0 => p=1 exactly; l subtracts n_masked (Sub) in-kernel.
// R11/12/14/15..17 lessons retained.  R18 FALSIFIED: never trade blocks/CU
// for per-block work in the 2-barrier loop.  R19: barrier count ~neutral at
// fixed occupancy; R9/R10 gemm_qkv "regressions" = container clock throttle
// (identical code+bytes, uniformly lower BW).  R20: attn full-kv blocks +
// direct AO write (deleted attn_merge/Osc/Lsc).
// R21: gemm_oproj SPLIT-K=2 (grid (16,64,2), 8 K-steps/block, 8 blocks/CU
// co-resident): small-M GEMM was serial-K latency-bound; partials P0/P1
// (P1 overlays dead Xkv), bias+residual absorbed into ln_kernel.  The
// total-time delta also finally measures oproj's true weight.
// ---------------------------------------------------------------------------

typedef __bf16 bf16x8_t  __attribute__((ext_vector_type(8)));
typedef float  f32x4_t   __attribute__((ext_vector_type(4)));
typedef float  f32x16_t  __attribute__((ext_vector_type(16)));

#define E_DIM 1024
#define NH    16
#define HD    64
#define SCALE_L2E 0.1803368804f   // (1/8) * log2(e)

__device__ __forceinline__ unsigned short f32_bf16(float f) {
    union { float f; unsigned int u; } v; v.f = f;
    unsigned int u = v.u;
    unsigned int r = (u + 0x7fffu + ((u >> 16) & 1u)) >> 16;  // RNE
    return (unsigned short)r;
}

__device__ __forceinline__ unsigned pack_bf16(float a, float b) {
    __bf16 x = (__bf16)a, y = (__bf16)b;
    unsigned short ux = __builtin_bit_cast(unsigned short, x);
    unsigned short uy = __builtin_bit_cast(unsigned short, y);
    return (unsigned)ux | ((unsigned)uy << 16);
}

// async global->LDS, 16B per lane; lds base must be wave-uniform
__device__ __forceinline__ void gld16(const unsigned short* g, unsigned short* l) {
    __builtin_amdgcn_global_load_lds(
        (const __attribute__((address_space(1))) unsigned int*)g,
        (__attribute__((address_space(3))) unsigned int*)l, 16, 0, 0);
}

__device__ __forceinline__ bf16x8_t ld16g(const unsigned short* p) {
    union { uint4 u; bf16x8_t f; } v;
    v.u = *reinterpret_cast<const uint4*>(p);
    return v.f;
}

// ------- fused fp32 -> bf16 casts (all 6 tensors) + mask count -------------
__global__ void cast_all(const float* __restrict__ q, const float* __restrict__ kv,
                         const float* __restrict__ wq, const float* __restrict__ wk,
                         const float* __restrict__ wv, const float* __restrict__ wo,
                         unsigned short* __restrict__ Xq, unsigned short* __restrict__ Xkv,
                         unsigned short* __restrict__ Wqb, unsigned short* __restrict__ Wkb,
                         unsigned short* __restrict__ Wvb, unsigned short* __restrict__ Wob,
                         const int* __restrict__ msk, float* __restrict__ Sub) {
    __shared__ int red[4];
    if (blockIdx.x >= 14336) {           // mask-count blocks (b = 0,1)
        int b = blockIdx.x - 14336, t = threadIdx.x;
        int s = 0;
#pragma unroll
        for (int k = 0; k < 16; k++) s += (msk[b * 4096 + k * 256 + t] != 0);
#pragma unroll
        for (int off = 32; off >= 1; off >>= 1) s += __shfl_xor(s, off, 64);
        if ((t & 63) == 0) red[t >> 6] = s;
        __syncthreads();
        if (t == 0)
            Sub[b] = (float)(4096 - (red[0] + red[1] + red[2] + red[3]));
        return;
    }
    long i = (long)blockIdx.x * 256 + threadIdx.x;   // float4 index
    const float* src; unsigned short* dst; long off;
    if (i < 2621440) {
        if (i < 524288) { src = q;  dst = Xq;  off = i; }
        else            { src = kv; dst = Xkv; off = i - 524288; }
    } else {
        long j = i - 2621440;
        int w = (int)(j >> 18); off = j & 262143;
        src = (w == 0) ? wq : (w == 1) ? wk : (w == 2) ? wv : wo;
        dst = (w == 0) ? Wqb : (w == 1) ? Wkb : (w == 2) ? Wvb : Wob;
    }
    float4 v = reinterpret_cast<const float4*>(src)[off];
    ushort4 o;
    o.x = f32_bf16(v.x); o.y = f32_bf16(v.y);
    o.z = f32_bf16(v.z); o.w = f32_bf16(v.w);
    reinterpret_cast<ushort4*>(dst)[off] = o;
}

// ---------------- GEMM bodies (m97-style staging) --------------------------
#define BK 64

// Fused Q + K + V projections, one launch of 1280 blocks, XCD-GROUPED
// (R7 form: separate K and V blocks keep VGPR 88 / LDS 32KB = 5 blocks/CU).
__global__ __launch_bounds__(256) void gemm_qkv(
    const unsigned short* __restrict__ Xq,
    const unsigned short* __restrict__ Xkv,
    const unsigned short* __restrict__ Wqb,
    const unsigned short* __restrict__ Wkb,
    const unsigned short* __restrict__ Wvb,
    const float* __restrict__ bq,
    const float* __restrict__ bk,
    const float* __restrict__ bv,
    unsigned short* __restrict__ Qout,
    unsigned short* __restrict__ Kout,
    unsigned short* __restrict__ Vout,
    const int* __restrict__ kvm)
{
    __shared__ __align__(16) unsigned short As[128 * BK];
    __shared__ __align__(16) unsigned short Bs[128 * BK];
    int bid  = blockIdx.x;
    int tid  = threadIdx.x;
    int lane = tid & 63;
    int wvu  = __builtin_amdgcn_readfirstlane(tid >> 6);
    int l15  = lane & 15, quad = lane >> 4, x7 = l15 & 7;

    if (bid < 1024) {
        // ---------------- K/V path (BM=BN=128), XCD-grouped ----------------
        int xcd  = bid & 7;
        int j    = bid >> 3;               // 0..127
        int mt   = xcd * 8 + (j >> 4);     // 0..63
        int sel  = j & 15;
        int isV  = sel >= 8;
        int m0   = mt * 128;
        int n0   = (sel & 7) * 128;
        const unsigned short* W = isV ? Wvb : Wkb;
        const float* bias = isV ? bv : bk;
        int wm   = ((tid >> 6) >> 1) * 64, wn = ((tid >> 6) & 1) * 64;

        f32x4_t acc[4][4];
#pragma unroll
        for (int i = 0; i < 4; i++)
#pragma unroll
            for (int jj = 0; jj < 4; jj++) acc[i][jj] = (f32x4_t)(0.f);

        for (int k0 = 0; k0 < 1024; k0 += BK) {
            __syncthreads();
#pragma unroll
            for (int i = 0; i < 4; i++) {
                int s = (i * 4 + wvu) * 64 + lane;
                int row = s >> 3, pcol = ((s & 7) ^ (row & 7)) << 3;
                gld16(&Xkv[(long)(m0 + row) * 1024 + k0 + pcol], &As[(i * 4 + wvu) * 512]);
                gld16(&W[(long)(n0 + row) * 1024 + k0 + pcol], &Bs[(i * 4 + wvu) * 512]);
            }
            __syncthreads();
            const char* Ab = (const char*)As;
            const char* Bb = (const char*)Bs;
#pragma unroll
            for (int ks = 0; ks < 2; ks++) {
                int pos = (((ks << 2) + quad) ^ x7) << 4;
                bf16x8_t af[4], bf[4];
#pragma unroll
                for (int mi = 0; mi < 4; mi++)
                    af[mi] = *reinterpret_cast<const bf16x8_t*>(
                        Ab + (wm + mi * 16 + l15) * 128 + pos);
#pragma unroll
                for (int ni = 0; ni < 4; ni++)
                    bf[ni] = *reinterpret_cast<const bf16x8_t*>(
                        Bb + (wn + ni * 16 + l15) * 128 + pos);
#pragma unroll
                for (int mi = 0; mi < 4; mi++)
#pragma unroll
                    for (int ni = 0; ni < 4; ni++)
                        acc[mi][ni] = __builtin_amdgcn_mfma_f32_16x16x32_bf16(
                            af[mi], bf[ni], acc[mi][ni], 0, 0, 0);
            }
        }
        // hoisted mask: mg = b*4096+s indexes kvm flat; int4 per mi
        int4 mk[4];
#pragma unroll
        for (int mi = 0; mi < 4; mi++) {
            int mg0 = m0 + wm + mi * 16 + quad * 4;
            mk[mi] = *reinterpret_cast<const int4*>(&kvm[mg0]);
        }
        if (!isV) {
#pragma unroll
            for (int mi = 0; mi < 4; mi++)
#pragma unroll
                for (int ni = 0; ni < 4; ni++) {
                    int n = n0 + wn + ni * 16 + l15;
                    float bvv = bias[n];
                    int h = n >> 6, d = n & 63;
#pragma unroll
                    for (int r = 0; r < 4; r++) {
                        int mg = m0 + wm + mi * 16 + quad * 4 + r;
                        int b = mg >> 12, s = mg & 4095;
                        unsigned short val = (&mk[mi].x)[r]
                            ? f32_bf16(acc[mi][ni][r] + bvv) : (unsigned short)0;
                        Kout[(((b * NH + h) << 12) + s) * HD + d] = val;
                    }
                }
        } else {
#pragma unroll
            for (int mi = 0; mi < 4; mi++)
#pragma unroll
                for (int ni = 0; ni < 4; ni++) {
                    int n = n0 + wn + ni * 16 + l15;
                    float bvv = bias[n];
                    int h = n >> 6, d = n & 63;
                    int mg0 = m0 + wm + mi * 16 + quad * 4;
                    int b = mg0 >> 12, s = mg0 & 4095;
                    ushort4 w;
                    w.x = mk[mi].x ? f32_bf16(acc[mi][ni][0] + bvv) : (unsigned short)0;
                    w.y = mk[mi].y ? f32_bf16(acc[mi][ni][1] + bvv) : (unsigned short)0;
                    w.z = mk[mi].z ? f32_bf16(acc[mi][ni][2] + bvv) : (unsigned short)0;
                    w.w = mk[mi].w ? f32_bf16(acc[mi][ni][3] + bvv) : (unsigned short)0;
                    *reinterpret_cast<ushort4*>(
                        &Vout[(((b * NH + h) * HD + d) << 12) + s]) = w;
                }
        }
    } else {
        // ---------------- Q path (BM=64, BN=128), XCD-grouped ----------------
        int t    = bid - 1024;
        int xcd  = bid & 7;                // == t & 7
        int j    = t >> 3;                 // 0..31
        int mt   = xcd * 4 + (j >> 3);     // 0..31
        int m0   = mt * 64;
        int n0   = (j & 7) * 128;
        int wm   = ((tid >> 6) >> 1) * 32, wn = ((tid >> 6) & 1) * 64;

        f32x4_t acc[2][4];
#pragma unroll
        for (int i = 0; i < 2; i++)
#pragma unroll
            for (int jj = 0; jj < 4; jj++) acc[i][jj] = (f32x4_t)(0.f);

        for (int k0 = 0; k0 < 1024; k0 += BK) {
            __syncthreads();
#pragma unroll
            for (int i = 0; i < 2; i++) {       // A: 512 slots
                int s = (i * 4 + wvu) * 64 + lane;
                int row = s >> 3, pcol = ((s & 7) ^ (row & 7)) << 3;
                gld16(&Xq[(long)(m0 + row) * 1024 + k0 + pcol], &As[(i * 4 + wvu) * 512]);
            }
#pragma unroll
            for (int i = 0; i < 4; i++) {       // B: 1024 slots
                int s = (i * 4 + wvu) * 64 + lane;
                int row = s >> 3, pcol = ((s & 7) ^ (row & 7)) << 3;
                gld16(&Wqb[(long)(n0 + row) * 1024 + k0 + pcol], &Bs[(i * 4 + wvu) * 512]);
            }
            __syncthreads();
            const char* Ab = (const char*)As;
            const char* Bb = (const char*)Bs;
#pragma unroll
            for (int ks = 0; ks < 2; ks++) {
                int pos = (((ks << 2) + quad) ^ x7) << 4;
                bf16x8_t af[2], bf[4];
#pragma unroll
                for (int mi = 0; mi < 2; mi++)
                    af[mi] = *reinterpret_cast<const bf16x8_t*>(
                        Ab + (wm + mi * 16 + l15) * 128 + pos);
#pragma unroll
                for (int ni = 0; ni < 4; ni++)
                    bf[ni] = *reinterpret_cast<const bf16x8_t*>(
                        Bb + (wn + ni * 16 + l15) * 128 + pos);
#pragma unroll
                for (int mi = 0; mi < 2; mi++)
#pragma unroll
                    for (int ni = 0; ni < 4; ni++)
                        acc[mi][ni] = __builtin_amdgcn_mfma_f32_16x16x32_bf16(
                            af[mi], bf[ni], acc[mi][ni], 0, 0, 0);
            }
        }
#pragma unroll
        for (int mi = 0; mi < 2; mi++)
#pragma unroll
            for (int ni = 0; ni < 4; ni++) {
                int n = n0 + wn + ni * 16 + l15;
                float bvq = bq[n];
                int h = n >> 6, d = n & 63;
#pragma unroll
                for (int r = 0; r < 4; r++) {
                    int mg = m0 + wm + mi * 16 + quad * 4 + r;
                    int b = mg >> 10, s = mg & 1023;
                    Qout[(((b * NH + h) << 10) + s) * HD + d] =
                        f32_bf16((acc[mi][ni][r] + bvq) * SCALE_L2E);
                }
            }
    }
}

// -------- O-proj GEMM, SPLIT-K=2, fp32 partials (no bias/resid) ------------
// grid (16, 64, 2) = 2048 blocks of 256 (8 blocks/CU co-resident).  Each
// block: BM=32 x BN=64 over K-range [z*512, z*512+512) = 8 K-steps.
// Partials P0/P1 summed (with bias + residual) in ln_kernel.
__global__ __launch_bounds__(256) void gemm_oproj(
    const unsigned short* __restrict__ A,
    const unsigned short* __restrict__ W,
    float* __restrict__ P0,
    float* __restrict__ P1)
{
    __shared__ __align__(16) unsigned short As[32 * BK];
    __shared__ __align__(16) unsigned short Bs[64 * BK];
    int tid  = threadIdx.x;
    int m0   = blockIdx.y * 32;
    int n0   = blockIdx.x * 64;
    int kc   = blockIdx.z;                 // K chunk 0/1
    int kbeg = kc * 512;
    int lane = tid & 63;
    int wvu  = __builtin_amdgcn_readfirstlane(tid >> 6);
    int l15  = lane & 15, quad = lane >> 4, x7 = l15 & 7;
    int wn   = (tid >> 6) * 16;

    f32x4_t acc[2];
    acc[0] = (f32x4_t)(0.f); acc[1] = (f32x4_t)(0.f);

    for (int k0 = kbeg; k0 < kbeg + 512; k0 += BK) {
        __syncthreads();
        {                                     // A: 256 slots (1 per lane)
            int s = wvu * 64 + lane;
            int row = s >> 3, pcol = ((s & 7) ^ (row & 7)) << 3;
            gld16(&A[(long)(m0 + row) * 1024 + k0 + pcol], &As[wvu * 512]);
        }
#pragma unroll
        for (int i = 0; i < 2; i++) {         // B: 512 slots
            int s = (i * 4 + wvu) * 64 + lane;
            int row = s >> 3, pcol = ((s & 7) ^ (row & 7)) << 3;
            gld16(&W[(long)(n0 + row) * 1024 + k0 + pcol], &Bs[(i * 4 + wvu) * 512]);
        }
        __syncthreads();
        const char* Ab = (const char*)As;
        const char* Bb = (const char*)Bs;
#pragma unroll
        for (int ks = 0; ks < 2; ks++) {
            int pos = (((ks << 2) + quad) ^ x7) << 4;
            bf16x8_t af[2], bf;
#pragma unroll
            for (int mi = 0; mi < 2; mi++)
                af[mi] = *reinterpret_cast<const bf16x8_t*>(
                    Ab + (mi * 16 + l15) * 128 + pos);
            bf = *reinterpret_cast<const bf16x8_t*>(
                Bb + (wn + l15) * 128 + pos);
#pragma unroll
            for (int mi = 0; mi < 2; mi++)
                acc[mi] = __builtin_amdgcn_mfma_f32_16x16x32_bf16(
                    af[mi], bf, acc[mi], 0, 0, 0);
        }
    }
    float* xo = kc ? P1 : P0;
    int n = n0 + wn + l15;
#pragma unroll
    for (int mi = 0; mi < 2; mi++)
#pragma unroll
        for (int r = 0; r < 4; r++) {
            int mg = m0 + mi * 16 + quad * 4 + r;
            xo[mg * 1024 + n] = acc[mi][r];
        }
}

// ---------------- flash attention: full-kv blocks, direct AO write ---------
// grid 512 blocks of 512 (8 waves).  Block = 64 q of one (b,h) x FULL 4096 kv
// (32 tiles of KVT=128).  Wave w: qsub = w&1 (32 q), kvsub = w>>1 in 0..3
// (32-kv strip of each tile).  2 blocks/CU (validated regime).  Complete l
// in-block => epilogue: 4-way kvsub merge via dead staging LDS, normalize
// (l - Sub[b]), bf16, transpose through T[64x66], direct 16B AO stores.
// Softmax: p = 2^s' via raw v_exp_f32.  P-exchange via permlane32_swap.
__global__ __launch_bounds__(512, 4) void attn_kernel(
    const unsigned short* __restrict__ Q,   // [B,NH,1024,64] pre-scaled
    const unsigned short* __restrict__ K,   // [B,NH,4096,64]  masked rows = 0
    const unsigned short* __restrict__ VT,  // [B,NH,64,4096]  masked cols = 0
    const float* __restrict__ Sub,          // [2] # masked kv per batch
    unsigned short* __restrict__ AO)        // [B,1024,E] bf16 attention out
{
    __shared__ __align__(16) union {
        struct { unsigned short Kb[2][8192]; unsigned short Vb[2][8192]; } st;
        struct { float OL[6][2048]; float ls[256]; unsigned short T[64 * 66]; } mg;
    } sm;

    int tid  = threadIdx.x;
    int lane = tid & 63;
    int w    = tid >> 6;
    int wvu  = __builtin_amdgcn_readfirstlane(w);
    int l31  = lane & 31, hw = lane >> 5;
    int qsub = w & 1, kvsub = w >> 1;        // qsub 0..1, kvsub 0..3

    // XCD-grouped: 4 (b,h) per XCD; the 16 q-tiles of one bh share its K/V in L2
    int bid  = blockIdx.x;
    int xcd  = bid & 7, gidx = bid >> 3;     // gidx 0..63
    int bh   = xcd * 4 + (gidx & 3);
    int q0   = (gidx >> 2) * 64;             // 16 q-tiles of 64
    int b    = bh >> 4, h = bh & 15;

    const unsigned short* Kg = K + (long)bh * 4096 * HD;
    const unsigned short* Vg = VT + (long)bh * HD * 4096;
    const unsigned short* Qb = Q + ((long)bh * 1024 + q0) * HD;

    // Q fragments (B-operand): B[n=q=l31][k=hw*8+j], 4 k-chunks of 16
    bf16x8_t qfr[4];
#pragma unroll
    for (int ks = 0; ks < 4; ks++)
        qfr[ks] = ld16g(Qb + (qsub * 32 + l31) * HD + ks * 16 + hw * 8);

    f32x16_t oacc[2];
    oacc[0] = (f32x16_t)(0.f); oacc[1] = (f32x16_t)(0.f);
    float l_run = 0.f;

    // stage one KVT=128 tile: K 128x64 (8 slots/row, XOR&7), V^T 64x128
    // (16 slots/row, XOR&15).  1024 slots of 16B each; 2 gld16/lane/tensor.
    auto stage = [&](int kt, int bufi) {
#pragma unroll
        for (int i = 0; i < 2; i++) {
            int s = (i * 8 + wvu) * 64 + lane;          // 0..1023
            int krow = s >> 3, kpc = ((s & 7) ^ (krow & 7)) << 3;
            gld16(&Kg[(long)(kt * 128 + krow) * HD + kpc],
                  &sm.st.Kb[bufi][(i * 8 + wvu) * 512]);
            int vrow = s >> 4, vpc = ((s & 15) ^ (vrow & 15)) << 3;
            gld16(&Vg[(long)vrow * 4096 + kt * 128 + vpc],
                  &sm.st.Vb[bufi][(i * 8 + wvu) * 512]);
        }
    };

    const char* Kc = (const char*)sm.st.Kb;
    const char* Vc = (const char*)sm.st.Vb;

    stage(0, 0);
#pragma unroll 2
    for (int kt = 0; kt < 32; kt++) {
        __syncthreads();                 // stage(kt) visible; compute(kt-1) done
        if (kt + 1 < 32) stage(kt + 1, (kt + 1) & 1);
        int bo = (kt & 1) * 16384;       // byte offset of current buffer

        // ---- S^T: C[kv32][q32], kv rows = kvsub*32 + l31 (0..127) ----
        f32x16_t sa = (f32x16_t)(0.f);
        int krow = kvsub * 32 + l31;
        __builtin_amdgcn_s_setprio(1);
#pragma unroll
        for (int ks = 0; ks < 4; ks++) {
            int phys = (ks * 2 + hw) ^ (krow & 7);
            bf16x8_t kf = *reinterpret_cast<const bf16x8_t*>(
                Kc + bo + krow * 128 + phys * 16);
            sa = __builtin_amdgcn_mfma_f32_32x32x16_bf16(kf, qfr[ks], sa, 0, 0, 0);
        }
        __builtin_amdgcn_s_setprio(0);

        // ---- softmax: p = 2^s' via raw v_exp_f32 (masked => p=1) ----
        float pv[16];
#pragma unroll
        for (int r = 0; r < 16; r++) {
            float e;
            asm("v_exp_f32 %0, %1" : "=v"(e) : "v"(sa[r]));
            pv[r] = e;
        }
        float s0 = (pv[0] + pv[1]) + (pv[2] + pv[3]);
        float s1 = (pv[4] + pv[5]) + (pv[6] + pv[7]);
        float s2 = (pv[8] + pv[9]) + (pv[10] + pv[11]);
        float s3 = (pv[12] + pv[13]) + (pv[14] + pv[15]);
        l_run += (s0 + s1) + (s2 + s3);
        unsigned pku[8];
#pragma unroll
        for (int s4 = 0; s4 < 4; s4++) {
            pku[s4 * 2 + 0] = pack_bf16(pv[s4 * 4 + 0], pv[s4 * 4 + 1]);
            pku[s4 * 2 + 1] = pack_bf16(pv[s4 * 4 + 2], pv[s4 * 4 + 3]);
        }

        // ---- PV: O^T[d][q] += V^T · P over this wave's 32-kv strip ----
        __builtin_amdgcn_s_setprio(1);
#pragma unroll
        for (int ks2 = 0; ks2 < 2; ks2++) {
            unsigned x0 = pku[(ks2 * 2) * 2 + 0];
            unsigned x1 = pku[(ks2 * 2) * 2 + 1];
            unsigned z0 = pku[(ks2 * 2 + 1) * 2 + 0];
            unsigned z1 = pku[(ks2 * 2 + 1) * 2 + 1];
            asm("v_permlane32_swap_b32 %0, %1" : "+v"(x0), "+v"(z0));
            asm("v_permlane32_swap_b32 %0, %1" : "+v"(x1), "+v"(z1));
            union { uint4 u; bf16x8_t f; } bw;
            bw.u.x = x0; bw.u.y = x1; bw.u.z = z0; bw.u.w = z1;
            int c = kvsub * 4 + ks2 * 2 + hw;            // kv 8-chunk 0..15
#pragma unroll
            for (int ds = 0; ds < 2; ds++) {
                int vrow = ds * 32 + l31;
                int phys = c ^ (vrow & 15);
                bf16x8_t va = *reinterpret_cast<const bf16x8_t*>(
                    Vc + bo + vrow * 256 + phys * 16);
                oacc[ds] = __builtin_amdgcn_mfma_f32_32x32x16_bf16(
                    va, bw.f, oacc[ds], 0, 0, 0);
            }
        }
        __builtin_amdgcn_s_setprio(0);
    }

    // ---- epilogue: 4-way kvsub merge, normalize, transpose, AO write ----
    l_run += __shfl_xor(l_run, 32, 64);      // combine hw halves (32-kv strip)
    __syncthreads();                          // staging dead; LDS reusable
    if (kvsub != 0) {
        float* OL = sm.mg.OL[(kvsub - 1) * 2 + qsub];
#pragma unroll
        for (int ds = 0; ds < 2; ds++)
#pragma unroll
            for (int r = 0; r < 16; r++) {
                int d = ds * 32 + (r & 3) + 8 * (r >> 2) + 4 * hw;
                OL[d * 32 + l31] = oacc[ds][r];
            }
        if (hw == 0) sm.mg.ls[(kvsub * 2 + qsub) * 32 + l31] = l_run;
    }
    __syncthreads();
    if (kvsub == 0) {
        float lt = l_run;
#pragma unroll
        for (int k = 1; k < 4; k++)
            lt += sm.mg.ls[(k * 2 + qsub) * 32 + l31];
        lt -= Sub[b];
        float inv = __builtin_amdgcn_rcpf(lt);
        inv = inv * (2.f - lt * inv);        // NR refine
        int q = qsub * 32 + l31;
#pragma unroll
        for (int ds = 0; ds < 2; ds++)
#pragma unroll
            for (int r = 0; r < 16; r++) {
                int d = ds * 32 + (r & 3) + 8 * (r >> 2) + 4 * hw;
                float o = oacc[ds][r];
#pragma unroll
                for (int k = 0; k < 3; k++)
                    o += sm.mg.OL[k * 2 + qsub][d * 32 + l31];
                sm.mg.T[q * 66 + d] = f32_bf16(o * inv);
            }
    }
    __syncthreads();
    // cooperative AO write: 512 threads, 64 rows x 4 chunks of 16B
    {
        int q2 = tid >> 3, c16 = (tid & 7) * 8;     // elements
        unsigned ov[4];
#pragma unroll
        for (int j = 0; j < 4; j++)
            ov[j] = *reinterpret_cast<const unsigned*>(&sm.mg.T[q2 * 66 + c16 + j * 2]);
        unsigned short* dst = &AO[((long)(b * 1024 + q0 + q2)) * E_DIM + h * HD + c16];
        reinterpret_cast<uint4*>(dst)[0] = make_uint4(ov[0], ov[1], ov[2], ov[3]);
    }
}

// -------- LayerNorm over E=1024 on x = P0 + P1 + bias_o + residual --------
__global__ __launch_bounds__(256) void ln_kernel(
    const float* __restrict__ p0, const float* __restrict__ p1,
    const float* __restrict__ resid, const float* __restrict__ bo,
    const float* __restrict__ g, const float* __restrict__ be,
    float* __restrict__ out)
{
    __shared__ float red[8];
    int row = blockIdx.x, tid = threadIdx.x;
    float4 a  = reinterpret_cast<const float4*>(p0)[row * 256 + tid];
    float4 b2 = reinterpret_cast<const float4*>(p1)[row * 256 + tid];
    float4 qv = reinterpret_cast<const float4*>(resid)[row * 256 + tid];
    float4 bb = reinterpret_cast<const float4*>(bo)[tid];
    float4 v;
    v.x = a.x + b2.x + qv.x + bb.x;
    v.y = a.y + b2.y + qv.y + bb.y;
    v.z = a.z + b2.z + qv.z + bb.z;
    v.w = a.w + b2.w + qv.w + bb.w;
    float s  = v.x + v.y + v.z + v.w;
    float sq = v.x * v.x + v.y * v.y + v.z * v.z + v.w * v.w;
#pragma unroll
    for (int off = 32; off >= 1; off >>= 1) {
        s  += __shfl_xor(s,  off, 64);
        sq += __shfl_xor(sq, off, 64);
    }
    if ((tid & 63) == 0) { red[tid >> 6] = s; red[4 + (tid >> 6)] = sq; }
    __syncthreads();
    s  = red[0] + red[1] + red[2] + red[3];
    sq = red[4] + red[5] + red[6] + red[7];
    float mu  = s * (1.f / 1024.f);
    float var = sq * (1.f / 1024.f) - mu * mu;
    float rs  = rsqrtf(var + 1e-5f);
    int c = tid * 4;
    float4 o;
    o.x = (v.x - mu) * rs * g[c]     + be[c];
    o.y = (v.y - mu) * rs * g[c + 1] + be[c + 1];
    o.z = (v.z - mu) * rs * g[c + 2] + be[c + 2];
    o.w = (v.w - mu) * rs * g[c + 3] + be[c + 3];
    reinterpret_cast<float4*>(out)[row * 256 + tid] = o;
}

// ---------------------------------------------------------------------------
extern "C" void kernel_launch(void* const* d_in, const int* in_sizes, int n_in,
                              void* d_out, int out_size, void* d_ws, size_t ws_size,
                              hipStream_t stream) {
    const float* query     = (const float*)d_in[0];
    const float* key_value = (const float*)d_in[1];
    const int*   kv_mask   = (const int*)d_in[2];
    const float* Wq = (const float*)d_in[3];
    const float* bq = (const float*)d_in[4];
    const float* Wk = (const float*)d_in[5];
    const float* bk = (const float*)d_in[6];
    const float* Wv = (const float*)d_in[7];
    const float* bv = (const float*)d_in[8];
    const float* Wo = (const float*)d_in[9];
    const float* bo = (const float*)d_in[10];
    const float* ln_g = (const float*)d_in[11];
    const float* ln_b = (const float*)d_in[12];
    float* out = (float*)d_out;

    // workspace layout (MiB).  Xr2 (o-proj partial 1) overlays the dead
    // Xkv region (4-12): Xkv is consumed by gemm_qkv, which completes
    // before gemm_oproj runs (stream-ordered).
    char* ws = (char*)d_ws;
    unsigned short* Xq  = (unsigned short*)(ws);                     // 0-4
    unsigned short* Xkv = (unsigned short*)(ws + (4ll  << 20));      // 4-20
    float*          Xr2 = (float*)(ws + (4ll  << 20));               // 4-12 (after qkv)
    unsigned short* Wqb = (unsigned short*)(ws + (20ll << 20));      // 20-22
    unsigned short* Wkb = (unsigned short*)(ws + (22ll << 20));      // 22-24
    unsigned short* Wvb = (unsigned short*)(ws + (24ll << 20));      // 24-26
    unsigned short* Kh  = (unsigned short*)(ws + (32ll << 20));      // 32-48
    unsigned short* VTh = (unsigned short*)(ws + (48ll << 20));      // 48-64
    unsigned short* AO  = (unsigned short*)(ws + (64ll << 20));      // 64-68
    float*          Xr  = (float*)(ws + (68ll << 20));               // 68-76
    float*          Sub = (float*)(ws + (77ll << 20));               // tiny
    unsigned short* Qh  = (unsigned short*)(ws + (80ll << 20));      // 80-84
    unsigned short* Wob = (unsigned short*)(ws + (84ll << 20));      // 84-86

    cast_all<<<14338, 256, 0, stream>>>(query, key_value, Wq, Wk, Wv, Wo,
                                        Xq, Xkv, Wqb, Wkb, Wvb, Wob,
                                        kv_mask, Sub);

    gemm_qkv<<<1280, 256, 0, stream>>>(Xq, Xkv, Wqb, Wkb, Wvb, bq, bk, bv,
                                       Qh, Kh, VTh, kv_mask);

    attn_kernel<<<512, 512, 0, stream>>>(Qh, Kh, VTh, Sub, AO);

    gemm_oproj<<<dim3(16, 64, 2), 256, 0, stream>>>(AO, Wob, Xr, Xr2);

    ln_kernel<<<2048, 256, 0, stream>>>(Xr, Xr2, query, bo, ln_g, ln_b, out);
}

// Round 12
// 227.788 us; speedup vs baseline: 1.0291x; 1.0291x over previous
//
#include <hip/hip_runtime.h>
#include <cstdint>

// ---------------------------------------------------------------------------
// CrossAttentionBlock: q/k/v proj (bf16 MFMA; K/V rows zeroed where masked;
// Q pre-scaled by log2(e)/8) -> flash attention (32x32 MFMA, exp2-only
// softmax, double-buffered DMA staging, 2 qsub x 4 kvsub wave split,
// in-block merge, in-kernel normalize + transpose + direct AO write)
// -> o proj (+bias+residual) -> LayerNorm.  B=2,SQ=1024,SKV=4096,E=1024.
// Softmax: p = 2^(s') with s' = K·(Q*log2(e)/8) bounded (|s'|<~10).
// Masked kv have K=V=0 => p=1 exactly; l subtracts n_masked (Sub) in-kernel.
// R11/12/14/15..17 lessons retained.  R18 FALSIFIED: never trade blocks/CU
// for per-block work in the 2-barrier loop.  R19: barrier count ~neutral at
// fixed occupancy; rocprof-replay throttling explains R9/R10 counter noise.
// R20: attn full-kv blocks + direct AO write (deleted attn_merge/Osc/Lsc),
// -1.5us.  R21 FALSIFIED: split-K oproj +4.8us (partial fp32 traffic +
// fatter ln > serial-K saving; oproj is small, ~10us).  R22: revert to the
// R20/R10 configuration - best measured (229.6us, on a slow container).
// ---------------------------------------------------------------------------

typedef __bf16 bf16x8_t  __attribute__((ext_vector_type(8)));
typedef float  f32x4_t   __attribute__((ext_vector_type(4)));
typedef float  f32x16_t  __attribute__((ext_vector_type(16)));

#define E_DIM 1024
#define NH    16
#define HD    64
#define SCALE_L2E 0.1803368804f   // (1/8) * log2(e)

__device__ __forceinline__ unsigned short f32_bf16(float f) {
    union { float f; unsigned int u; } v; v.f = f;
    unsigned int u = v.u;
    unsigned int r = (u + 0x7fffu + ((u >> 16) & 1u)) >> 16;  // RNE
    return (unsigned short)r;
}

__device__ __forceinline__ unsigned pack_bf16(float a, float b) {
    __bf16 x = (__bf16)a, y = (__bf16)b;
    unsigned short ux = __builtin_bit_cast(unsigned short, x);
    unsigned short uy = __builtin_bit_cast(unsigned short, y);
    return (unsigned)ux | ((unsigned)uy << 16);
}

// async global->LDS, 16B per lane; lds base must be wave-uniform
__device__ __forceinline__ void gld16(const unsigned short* g, unsigned short* l) {
    __builtin_amdgcn_global_load_lds(
        (const __attribute__((address_space(1))) unsigned int*)g,
        (__attribute__((address_space(3))) unsigned int*)l, 16, 0, 0);
}

__device__ __forceinline__ bf16x8_t ld16g(const unsigned short* p) {
    union { uint4 u; bf16x8_t f; } v;
    v.u = *reinterpret_cast<const uint4*>(p);
    return v.f;
}

// ------- fused fp32 -> bf16 casts (all 6 tensors) + mask count -------------
__global__ void cast_all(const float* __restrict__ q, const float* __restrict__ kv,
                         const float* __restrict__ wq, const float* __restrict__ wk,
                         const float* __restrict__ wv, const float* __restrict__ wo,
                         unsigned short* __restrict__ Xq, unsigned short* __restrict__ Xkv,
                         unsigned short* __restrict__ Wqb, unsigned short* __restrict__ Wkb,
                         unsigned short* __restrict__ Wvb, unsigned short* __restrict__ Wob,
                         const int* __restrict__ msk, float* __restrict__ Sub) {
    __shared__ int red[4];
    if (blockIdx.x >= 14336) {           // mask-count blocks (b = 0,1)
        int b = blockIdx.x - 14336, t = threadIdx.x;
        int s = 0;
#pragma unroll
        for (int k = 0; k < 16; k++) s += (msk[b * 4096 + k * 256 + t] != 0);
#pragma unroll
        for (int off = 32; off >= 1; off >>= 1) s += __shfl_xor(s, off, 64);
        if ((t & 63) == 0) red[t >> 6] = s;
        __syncthreads();
        if (t == 0)
            Sub[b] = (float)(4096 - (red[0] + red[1] + red[2] + red[3]));
        return;
    }
    long i = (long)blockIdx.x * 256 + threadIdx.x;   // float4 index
    const float* src; unsigned short* dst; long off;
    if (i < 2621440) {
        if (i < 524288) { src = q;  dst = Xq;  off = i; }
        else            { src = kv; dst = Xkv; off = i - 524288; }
    } else {
        long j = i - 2621440;
        int w = (int)(j >> 18); off = j & 262143;
        src = (w == 0) ? wq : (w == 1) ? wk : (w == 2) ? wv : wo;
        dst = (w == 0) ? Wqb : (w == 1) ? Wkb : (w == 2) ? Wvb : Wob;
    }
    float4 v = reinterpret_cast<const float4*>(src)[off];
    ushort4 o;
    o.x = f32_bf16(v.x); o.y = f32_bf16(v.y);
    o.z = f32_bf16(v.z); o.w = f32_bf16(v.w);
    reinterpret_cast<ushort4*>(dst)[off] = o;
}

// ---------------- GEMM bodies (m97-style staging) --------------------------
#define BK 64

// Fused Q + K + V projections, one launch of 1280 blocks, XCD-GROUPED
// (R7 form: separate K and V blocks keep VGPR 88 / LDS 32KB = 5 blocks/CU).
__global__ __launch_bounds__(256) void gemm_qkv(
    const unsigned short* __restrict__ Xq,
    const unsigned short* __restrict__ Xkv,
    const unsigned short* __restrict__ Wqb,
    const unsigned short* __restrict__ Wkb,
    const unsigned short* __restrict__ Wvb,
    const float* __restrict__ bq,
    const float* __restrict__ bk,
    const float* __restrict__ bv,
    unsigned short* __restrict__ Qout,
    unsigned short* __restrict__ Kout,
    unsigned short* __restrict__ Vout,
    const int* __restrict__ kvm)
{
    __shared__ __align__(16) unsigned short As[128 * BK];
    __shared__ __align__(16) unsigned short Bs[128 * BK];
    int bid  = blockIdx.x;
    int tid  = threadIdx.x;
    int lane = tid & 63;
    int wvu  = __builtin_amdgcn_readfirstlane(tid >> 6);
    int l15  = lane & 15, quad = lane >> 4, x7 = l15 & 7;

    if (bid < 1024) {
        // ---------------- K/V path (BM=BN=128), XCD-grouped ----------------
        int xcd  = bid & 7;
        int j    = bid >> 3;               // 0..127
        int mt   = xcd * 8 + (j >> 4);     // 0..63
        int sel  = j & 15;
        int isV  = sel >= 8;
        int m0   = mt * 128;
        int n0   = (sel & 7) * 128;
        const unsigned short* W = isV ? Wvb : Wkb;
        const float* bias = isV ? bv : bk;
        int wm   = ((tid >> 6) >> 1) * 64, wn = ((tid >> 6) & 1) * 64;

        f32x4_t acc[4][4];
#pragma unroll
        for (int i = 0; i < 4; i++)
#pragma unroll
            for (int jj = 0; jj < 4; jj++) acc[i][jj] = (f32x4_t)(0.f);

        for (int k0 = 0; k0 < 1024; k0 += BK) {
            __syncthreads();
#pragma unroll
            for (int i = 0; i < 4; i++) {
                int s = (i * 4 + wvu) * 64 + lane;
                int row = s >> 3, pcol = ((s & 7) ^ (row & 7)) << 3;
                gld16(&Xkv[(long)(m0 + row) * 1024 + k0 + pcol], &As[(i * 4 + wvu) * 512]);
                gld16(&W[(long)(n0 + row) * 1024 + k0 + pcol], &Bs[(i * 4 + wvu) * 512]);
            }
            __syncthreads();
            const char* Ab = (const char*)As;
            const char* Bb = (const char*)Bs;
#pragma unroll
            for (int ks = 0; ks < 2; ks++) {
                int pos = (((ks << 2) + quad) ^ x7) << 4;
                bf16x8_t af[4], bf[4];
#pragma unroll
                for (int mi = 0; mi < 4; mi++)
                    af[mi] = *reinterpret_cast<const bf16x8_t*>(
                        Ab + (wm + mi * 16 + l15) * 128 + pos);
#pragma unroll
                for (int ni = 0; ni < 4; ni++)
                    bf[ni] = *reinterpret_cast<const bf16x8_t*>(
                        Bb + (wn + ni * 16 + l15) * 128 + pos);
#pragma unroll
                for (int mi = 0; mi < 4; mi++)
#pragma unroll
                    for (int ni = 0; ni < 4; ni++)
                        acc[mi][ni] = __builtin_amdgcn_mfma_f32_16x16x32_bf16(
                            af[mi], bf[ni], acc[mi][ni], 0, 0, 0);
            }
        }
        // hoisted mask: mg = b*4096+s indexes kvm flat; int4 per mi
        int4 mk[4];
#pragma unroll
        for (int mi = 0; mi < 4; mi++) {
            int mg0 = m0 + wm + mi * 16 + quad * 4;
            mk[mi] = *reinterpret_cast<const int4*>(&kvm[mg0]);
        }
        if (!isV) {
#pragma unroll
            for (int mi = 0; mi < 4; mi++)
#pragma unroll
                for (int ni = 0; ni < 4; ni++) {
                    int n = n0 + wn + ni * 16 + l15;
                    float bvv = bias[n];
                    int h = n >> 6, d = n & 63;
#pragma unroll
                    for (int r = 0; r < 4; r++) {
                        int mg = m0 + wm + mi * 16 + quad * 4 + r;
                        int b = mg >> 12, s = mg & 4095;
                        unsigned short val = (&mk[mi].x)[r]
                            ? f32_bf16(acc[mi][ni][r] + bvv) : (unsigned short)0;
                        Kout[(((b * NH + h) << 12) + s) * HD + d] = val;
                    }
                }
        } else {
#pragma unroll
            for (int mi = 0; mi < 4; mi++)
#pragma unroll
                for (int ni = 0; ni < 4; ni++) {
                    int n = n0 + wn + ni * 16 + l15;
                    float bvv = bias[n];
                    int h = n >> 6, d = n & 63;
                    int mg0 = m0 + wm + mi * 16 + quad * 4;
                    int b = mg0 >> 12, s = mg0 & 4095;
                    ushort4 w;
                    w.x = mk[mi].x ? f32_bf16(acc[mi][ni][0] + bvv) : (unsigned short)0;
                    w.y = mk[mi].y ? f32_bf16(acc[mi][ni][1] + bvv) : (unsigned short)0;
                    w.z = mk[mi].z ? f32_bf16(acc[mi][ni][2] + bvv) : (unsigned short)0;
                    w.w = mk[mi].w ? f32_bf16(acc[mi][ni][3] + bvv) : (unsigned short)0;
                    *reinterpret_cast<ushort4*>(
                        &Vout[(((b * NH + h) * HD + d) << 12) + s]) = w;
                }
        }
    } else {
        // ---------------- Q path (BM=64, BN=128), XCD-grouped ----------------
        int t    = bid - 1024;
        int xcd  = bid & 7;                // == t & 7
        int j    = t >> 3;                 // 0..31
        int mt   = xcd * 4 + (j >> 3);     // 0..31
        int m0   = mt * 64;
        int n0   = (j & 7) * 128;
        int wm   = ((tid >> 6) >> 1) * 32, wn = ((tid >> 6) & 1) * 64;

        f32x4_t acc[2][4];
#pragma unroll
        for (int i = 0; i < 2; i++)
#pragma unroll
            for (int jj = 0; jj < 4; jj++) acc[i][jj] = (f32x4_t)(0.f);

        for (int k0 = 0; k0 < 1024; k0 += BK) {
            __syncthreads();
#pragma unroll
            for (int i = 0; i < 2; i++) {       // A: 512 slots
                int s = (i * 4 + wvu) * 64 + lane;
                int row = s >> 3, pcol = ((s & 7) ^ (row & 7)) << 3;
                gld16(&Xq[(long)(m0 + row) * 1024 + k0 + pcol], &As[(i * 4 + wvu) * 512]);
            }
#pragma unroll
            for (int i = 0; i < 4; i++) {       // B: 1024 slots
                int s = (i * 4 + wvu) * 64 + lane;
                int row = s >> 3, pcol = ((s & 7) ^ (row & 7)) << 3;
                gld16(&Wqb[(long)(n0 + row) * 1024 + k0 + pcol], &Bs[(i * 4 + wvu) * 512]);
            }
            __syncthreads();
            const char* Ab = (const char*)As;
            const char* Bb = (const char*)Bs;
#pragma unroll
            for (int ks = 0; ks < 2; ks++) {
                int pos = (((ks << 2) + quad) ^ x7) << 4;
                bf16x8_t af[2], bf[4];
#pragma unroll
                for (int mi = 0; mi < 2; mi++)
                    af[mi] = *reinterpret_cast<const bf16x8_t*>(
                        Ab + (wm + mi * 16 + l15) * 128 + pos);
#pragma unroll
                for (int ni = 0; ni < 4; ni++)
                    bf[ni] = *reinterpret_cast<const bf16x8_t*>(
                        Bb + (wn + ni * 16 + l15) * 128 + pos);
#pragma unroll
                for (int mi = 0; mi < 2; mi++)
#pragma unroll
                    for (int ni = 0; ni < 4; ni++)
                        acc[mi][ni] = __builtin_amdgcn_mfma_f32_16x16x32_bf16(
                            af[mi], bf[ni], acc[mi][ni], 0, 0, 0);
            }
        }
#pragma unroll
        for (int mi = 0; mi < 2; mi++)
#pragma unroll
            for (int ni = 0; ni < 4; ni++) {
                int n = n0 + wn + ni * 16 + l15;
                float bvq = bq[n];
                int h = n >> 6, d = n & 63;
#pragma unroll
                for (int r = 0; r < 4; r++) {
                    int mg = m0 + wm + mi * 16 + quad * 4 + r;
                    int b = mg >> 10, s = mg & 1023;
                    Qout[(((b * NH + h) << 10) + s) * HD + d] =
                        f32_bf16((acc[mi][ni][r] + bvq) * SCALE_L2E);
                }
            }
    }
}

// -------- O-proj GEMM + bias + residual -> fp32, BM=32 x BN=64 -------------
__global__ __launch_bounds__(256) void gemm_oproj(
    const unsigned short* __restrict__ A,
    const unsigned short* __restrict__ W,
    const float* __restrict__ bias,
    const float* __restrict__ resid,
    float* __restrict__ xout)
{
    __shared__ __align__(16) unsigned short As[32 * BK];
    __shared__ __align__(16) unsigned short Bs[64 * BK];
    int tid  = threadIdx.x;
    int m0   = blockIdx.y * 32;
    int n0   = blockIdx.x * 64;
    int lane = tid & 63;
    int wvu  = __builtin_amdgcn_readfirstlane(tid >> 6);
    int l15  = lane & 15, quad = lane >> 4, x7 = l15 & 7;
    int wn   = (tid >> 6) * 16;

    f32x4_t acc[2];
    acc[0] = (f32x4_t)(0.f); acc[1] = (f32x4_t)(0.f);

    for (int k0 = 0; k0 < 1024; k0 += BK) {
        __syncthreads();
        {                                     // A: 256 slots (1 per lane)
            int s = wvu * 64 + lane;
            int row = s >> 3, pcol = ((s & 7) ^ (row & 7)) << 3;
            gld16(&A[(long)(m0 + row) * 1024 + k0 + pcol], &As[wvu * 512]);
        }
#pragma unroll
        for (int i = 0; i < 2; i++) {         // B: 512 slots
            int s = (i * 4 + wvu) * 64 + lane;
            int row = s >> 3, pcol = ((s & 7) ^ (row & 7)) << 3;
            gld16(&W[(long)(n0 + row) * 1024 + k0 + pcol], &Bs[(i * 4 + wvu) * 512]);
        }
        __syncthreads();
        const char* Ab = (const char*)As;
        const char* Bb = (const char*)Bs;
#pragma unroll
        for (int ks = 0; ks < 2; ks++) {
            int pos = (((ks << 2) + quad) ^ x7) << 4;
            bf16x8_t af[2], bf;
#pragma unroll
            for (int mi = 0; mi < 2; mi++)
                af[mi] = *reinterpret_cast<const bf16x8_t*>(
                    Ab + (mi * 16 + l15) * 128 + pos);
            bf = *reinterpret_cast<const bf16x8_t*>(
                Bb + (wn + l15) * 128 + pos);
#pragma unroll
            for (int mi = 0; mi < 2; mi++)
                acc[mi] = __builtin_amdgcn_mfma_f32_16x16x32_bf16(
                    af[mi], bf, acc[mi], 0, 0, 0);
        }
    }
    int n = n0 + wn + l15;
    float bv = bias[n];
#pragma unroll
    for (int mi = 0; mi < 2; mi++)
#pragma unroll
        for (int r = 0; r < 4; r++) {
            int mg = m0 + mi * 16 + quad * 4 + r;
            xout[mg * 1024 + n] = acc[mi][r] + bv + resid[mg * 1024 + n];
        }
}

// ---------------- flash attention: full-kv blocks, direct AO write ---------
// grid 512 blocks of 512 (8 waves).  Block = 64 q of one (b,h) x FULL 4096 kv
// (32 tiles of KVT=128).  Wave w: qsub = w&1 (32 q), kvsub = w>>1 in 0..3
// (32-kv strip of each tile).  2 blocks/CU (validated regime).  Complete l
// in-block => epilogue: 4-way kvsub merge via dead staging LDS, normalize
// (l - Sub[b]), bf16, transpose through T[64x66], direct 16B AO stores.
// Softmax: p = 2^s' via raw v_exp_f32.  P-exchange via permlane32_swap.
__global__ __launch_bounds__(512, 4) void attn_kernel(
    const unsigned short* __restrict__ Q,   // [B,NH,1024,64] pre-scaled
    const unsigned short* __restrict__ K,   // [B,NH,4096,64]  masked rows = 0
    const unsigned short* __restrict__ VT,  // [B,NH,64,4096]  masked cols = 0
    const float* __restrict__ Sub,          // [2] # masked kv per batch
    unsigned short* __restrict__ AO)        // [B,1024,E] bf16 attention out
{
    __shared__ __align__(16) union {
        struct { unsigned short Kb[2][8192]; unsigned short Vb[2][8192]; } st;
        struct { float OL[6][2048]; float ls[256]; unsigned short T[64 * 66]; } mg;
    } sm;

    int tid  = threadIdx.x;
    int lane = tid & 63;
    int w    = tid >> 6;
    int wvu  = __builtin_amdgcn_readfirstlane(w);
    int l31  = lane & 31, hw = lane >> 5;
    int qsub = w & 1, kvsub = w >> 1;        // qsub 0..1, kvsub 0..3

    // XCD-grouped: 4 (b,h) per XCD; the 16 q-tiles of one bh share its K/V in L2
    int bid  = blockIdx.x;
    int xcd  = bid & 7, gidx = bid >> 3;     // gidx 0..63
    int bh   = xcd * 4 + (gidx & 3);
    int q0   = (gidx >> 2) * 64;             // 16 q-tiles of 64
    int b    = bh >> 4, h = bh & 15;

    const unsigned short* Kg = K + (long)bh * 4096 * HD;
    const unsigned short* Vg = VT + (long)bh * HD * 4096;
    const unsigned short* Qb = Q + ((long)bh * 1024 + q0) * HD;

    // Q fragments (B-operand): B[n=q=l31][k=hw*8+j], 4 k-chunks of 16
    bf16x8_t qfr[4];
#pragma unroll
    for (int ks = 0; ks < 4; ks++)
        qfr[ks] = ld16g(Qb + (qsub * 32 + l31) * HD + ks * 16 + hw * 8);

    f32x16_t oacc[2];
    oacc[0] = (f32x16_t)(0.f); oacc[1] = (f32x16_t)(0.f);
    float l_run = 0.f;

    // stage one KVT=128 tile: K 128x64 (8 slots/row, XOR&7), V^T 64x128
    // (16 slots/row, XOR&15).  1024 slots of 16B each; 2 gld16/lane/tensor.
    auto stage = [&](int kt, int bufi) {
#pragma unroll
        for (int i = 0; i < 2; i++) {
            int s = (i * 8 + wvu) * 64 + lane;          // 0..1023
            int krow = s >> 3, kpc = ((s & 7) ^ (krow & 7)) << 3;
            gld16(&Kg[(long)(kt * 128 + krow) * HD + kpc],
                  &sm.st.Kb[bufi][(i * 8 + wvu) * 512]);
            int vrow = s >> 4, vpc = ((s & 15) ^ (vrow & 15)) << 3;
            gld16(&Vg[(long)vrow * 4096 + kt * 128 + vpc],
                  &sm.st.Vb[bufi][(i * 8 + wvu) * 512]);
        }
    };

    const char* Kc = (const char*)sm.st.Kb;
    const char* Vc = (const char*)sm.st.Vb;

    stage(0, 0);
#pragma unroll 2
    for (int kt = 0; kt < 32; kt++) {
        __syncthreads();                 // stage(kt) visible; compute(kt-1) done
        if (kt + 1 < 32) stage(kt + 1, (kt + 1) & 1);
        int bo = (kt & 1) * 16384;       // byte offset of current buffer

        // ---- S^T: C[kv32][q32], kv rows = kvsub*32 + l31 (0..127) ----
        f32x16_t sa = (f32x16_t)(0.f);
        int krow = kvsub * 32 + l31;
        __builtin_amdgcn_s_setprio(1);
#pragma unroll
        for (int ks = 0; ks < 4; ks++) {
            int phys = (ks * 2 + hw) ^ (krow & 7);
            bf16x8_t kf = *reinterpret_cast<const bf16x8_t*>(
                Kc + bo + krow * 128 + phys * 16);
            sa = __builtin_amdgcn_mfma_f32_32x32x16_bf16(kf, qfr[ks], sa, 0, 0, 0);
        }
        __builtin_amdgcn_s_setprio(0);

        // ---- softmax: p = 2^s' via raw v_exp_f32 (masked => p=1) ----
        float pv[16];
#pragma unroll
        for (int r = 0; r < 16; r++) {
            float e;
            asm("v_exp_f32 %0, %1" : "=v"(e) : "v"(sa[r]));
            pv[r] = e;
        }
        float s0 = (pv[0] + pv[1]) + (pv[2] + pv[3]);
        float s1 = (pv[4] + pv[5]) + (pv[6] + pv[7]);
        float s2 = (pv[8] + pv[9]) + (pv[10] + pv[11]);
        float s3 = (pv[12] + pv[13]) + (pv[14] + pv[15]);
        l_run += (s0 + s1) + (s2 + s3);
        unsigned pku[8];
#pragma unroll
        for (int s4 = 0; s4 < 4; s4++) {
            pku[s4 * 2 + 0] = pack_bf16(pv[s4 * 4 + 0], pv[s4 * 4 + 1]);
            pku[s4 * 2 + 1] = pack_bf16(pv[s4 * 4 + 2], pv[s4 * 4 + 3]);
        }

        // ---- PV: O^T[d][q] += V^T · P over this wave's 32-kv strip ----
        __builtin_amdgcn_s_setprio(1);
#pragma unroll
        for (int ks2 = 0; ks2 < 2; ks2++) {
            unsigned x0 = pku[(ks2 * 2) * 2 + 0];
            unsigned x1 = pku[(ks2 * 2) * 2 + 1];
            unsigned z0 = pku[(ks2 * 2 + 1) * 2 + 0];
            unsigned z1 = pku[(ks2 * 2 + 1) * 2 + 1];
            asm("v_permlane32_swap_b32 %0, %1" : "+v"(x0), "+v"(z0));
            asm("v_permlane32_swap_b32 %0, %1" : "+v"(x1), "+v"(z1));
            union { uint4 u; bf16x8_t f; } bw;
            bw.u.x = x0; bw.u.y = x1; bw.u.z = z0; bw.u.w = z1;
            int c = kvsub * 4 + ks2 * 2 + hw;            // kv 8-chunk 0..15
#pragma unroll
            for (int ds = 0; ds < 2; ds++) {
                int vrow = ds * 32 + l31;
                int phys = c ^ (vrow & 15);
                bf16x8_t va = *reinterpret_cast<const bf16x8_t*>(
                    Vc + bo + vrow * 256 + phys * 16);
                oacc[ds] = __builtin_amdgcn_mfma_f32_32x32x16_bf16(
                    va, bw.f, oacc[ds], 0, 0, 0);
            }
        }
        __builtin_amdgcn_s_setprio(0);
    }

    // ---- epilogue: 4-way kvsub merge, normalize, transpose, AO write ----
    l_run += __shfl_xor(l_run, 32, 64);      // combine hw halves (32-kv strip)
    __syncthreads();                          // staging dead; LDS reusable
    if (kvsub != 0) {
        float* OL = sm.mg.OL[(kvsub - 1) * 2 + qsub];
#pragma unroll
        for (int ds = 0; ds < 2; ds++)
#pragma unroll
            for (int r = 0; r < 16; r++) {
                int d = ds * 32 + (r & 3) + 8 * (r >> 2) + 4 * hw;
                OL[d * 32 + l31] = oacc[ds][r];
            }
        if (hw == 0) sm.mg.ls[(kvsub * 2 + qsub) * 32 + l31] = l_run;
    }
    __syncthreads();
    if (kvsub == 0) {
        float lt = l_run;
#pragma unroll
        for (int k = 1; k < 4; k++)
            lt += sm.mg.ls[(k * 2 + qsub) * 32 + l31];
        lt -= Sub[b];
        float inv = __builtin_amdgcn_rcpf(lt);
        inv = inv * (2.f - lt * inv);        // NR refine
        int q = qsub * 32 + l31;
#pragma unroll
        for (int ds = 0; ds < 2; ds++)
#pragma unroll
            for (int r = 0; r < 16; r++) {
                int d = ds * 32 + (r & 3) + 8 * (r >> 2) + 4 * hw;
                float o = oacc[ds][r];
#pragma unroll
                for (int k = 0; k < 3; k++)
                    o += sm.mg.OL[k * 2 + qsub][d * 32 + l31];
                sm.mg.T[q * 66 + d] = f32_bf16(o * inv);
            }
    }
    __syncthreads();
    // cooperative AO write: 512 threads, 64 rows x 4 chunks of 16B
    {
        int q2 = tid >> 3, c16 = (tid & 7) * 8;     // elements
        unsigned ov[4];
#pragma unroll
        for (int j = 0; j < 4; j++)
            ov[j] = *reinterpret_cast<const unsigned*>(&sm.mg.T[q2 * 66 + c16 + j * 2]);
        unsigned short* dst = &AO[((long)(b * 1024 + q0 + q2)) * E_DIM + h * HD + c16];
        reinterpret_cast<uint4*>(dst)[0] = make_uint4(ov[0], ov[1], ov[2], ov[3]);
    }
}

// ---------------- LayerNorm over E=1024 ------------------------------------
__global__ __launch_bounds__(256) void ln_kernel(
    const float* __restrict__ x, const float* __restrict__ g,
    const float* __restrict__ be, float* __restrict__ out)
{
    __shared__ float red[8];
    int row = blockIdx.x, tid = threadIdx.x;
    float4 v = reinterpret_cast<const float4*>(x)[row * 256 + tid];
    float s  = v.x + v.y + v.z + v.w;
    float sq = v.x * v.x + v.y * v.y + v.z * v.z + v.w * v.w;
#pragma unroll
    for (int off = 32; off >= 1; off >>= 1) {
        s  += __shfl_xor(s,  off, 64);
        sq += __shfl_xor(sq, off, 64);
    }
    if ((tid & 63) == 0) { red[tid >> 6] = s; red[4 + (tid >> 6)] = sq; }
    __syncthreads();
    s  = red[0] + red[1] + red[2] + red[3];
    sq = red[4] + red[5] + red[6] + red[7];
    float mu  = s * (1.f / 1024.f);
    float var = sq * (1.f / 1024.f) - mu * mu;
    float rs  = rsqrtf(var + 1e-5f);
    int c = tid * 4;
    float4 o;
    o.x = (v.x - mu) * rs * g[c]     + be[c];
    o.y = (v.y - mu) * rs * g[c + 1] + be[c + 1];
    o.z = (v.z - mu) * rs * g[c + 2] + be[c + 2];
    o.w = (v.w - mu) * rs * g[c + 3] + be[c + 3];
    reinterpret_cast<float4*>(out)[row * 256 + tid] = o;
}

// ---------------------------------------------------------------------------
extern "C" void kernel_launch(void* const* d_in, const int* in_sizes, int n_in,
                              void* d_out, int out_size, void* d_ws, size_t ws_size,
                              hipStream_t stream) {
    const float* query     = (const float*)d_in[0];
    const float* key_value = (const float*)d_in[1];
    const int*   kv_mask   = (const int*)d_in[2];
    const float* Wq = (const float*)d_in[3];
    const float* bq = (const float*)d_in[4];
    const float* Wk = (const float*)d_in[5];
    const float* bk = (const float*)d_in[6];
    const float* Wv = (const float*)d_in[7];
    const float* bv = (const float*)d_in[8];
    const float* Wo = (const float*)d_in[9];
    const float* bo = (const float*)d_in[10];
    const float* ln_g = (const float*)d_in[11];
    const float* ln_b = (const float*)d_in[12];
    float* out = (float*)d_out;

    // workspace layout (MiB).
    char* ws = (char*)d_ws;
    unsigned short* Xq  = (unsigned short*)(ws);                     // 0-4
    unsigned short* Xkv = (unsigned short*)(ws + (4ll  << 20));      // 4-20
    unsigned short* Wqb = (unsigned short*)(ws + (20ll << 20));      // 20-22
    unsigned short* Wkb = (unsigned short*)(ws + (22ll << 20));      // 22-24
    unsigned short* Wvb = (unsigned short*)(ws + (24ll << 20));      // 24-26
    unsigned short* Kh  = (unsigned short*)(ws + (32ll << 20));      // 32-48
    unsigned short* VTh = (unsigned short*)(ws + (48ll << 20));      // 48-64
    unsigned short* AO  = (unsigned short*)(ws + (64ll << 20));      // 64-68
    float*          Xr  = (float*)(ws + (68ll << 20));               // 68-76
    float*          Sub = (float*)(ws + (77ll << 20));               // tiny
    unsigned short* Qh  = (unsigned short*)(ws + (80ll << 20));      // 80-84
    unsigned short* Wob = (unsigned short*)(ws + (84ll << 20));      // 84-86

    cast_all<<<14338, 256, 0, stream>>>(query, key_value, Wq, Wk, Wv, Wo,
                                        Xq, Xkv, Wqb, Wkb, Wvb, Wob,
                                        kv_mask, Sub);

    gemm_qkv<<<1280, 256, 0, stream>>>(Xq, Xkv, Wqb, Wkb, Wvb, bq, bk, bv,
                                       Qh, Kh, VTh, kv_mask);

    attn_kernel<<<512, 512, 0, stream>>>(Qh, Kh, VTh, Sub, AO);

    gemm_oproj<<<dim3(16, 64), 256, 0, stream>>>(AO, Wob, bo, query, Xr);

    ln_kernel<<<2048, 256, 0, stream>>>(Xr, ln_g, ln_b, out);
}